// Round 4
// baseline (998.373 us; speedup 1.0000x reference)
//
#include <hip/hip_runtime.h>
#include <hip/hip_bf16.h>

// ---------------------------------------------------------------------------
// BYOGPT forward: embed+PE -> 4x[QKV proj, flash-attn, LN, lin, LN] -> unembed
// B=2 S=1024 D=768 H=12 Dh=64 V=50257. bf16 MFMA GEMMs, fp32 residual/LN.
// R4: unembed on an m201-style 8-phase 256x256 GEMM — per-quadrant phases,
//     half-tile staging into just-freed slots, counted vmcnt(6/8), T2+T5+T1.
// ---------------------------------------------------------------------------

#define VOCAB 50257
#define DM 768
#define NL 4
#define NH 12
#define DH 64
#define SEQ 1024
#define BATCH 2
#define ROWS (BATCH * SEQ)   // 2048
#define QKVN (3 * DM)        // 2304

typedef __attribute__((ext_vector_type(8))) short short8;
typedef __attribute__((ext_vector_type(4))) float f32x4;

__device__ __forceinline__ unsigned short f2bf(float f) {
    union { float f; unsigned u; } v; v.f = f;
    unsigned r = v.u + 0x7FFFu + ((v.u >> 16) & 1u);   // RNE
    return (unsigned short)(r >> 16);
}

#define GLOAD16(gp, lp)                                                        \
    __builtin_amdgcn_global_load_lds(                                          \
        (const __attribute__((address_space(1))) unsigned int*)(gp),           \
        (__attribute__((address_space(3))) unsigned int*)(lp), 16, 0, 0)

#define BARRIER() asm volatile("s_barrier" ::: "memory")
#define LGKM0()   asm volatile("s_waitcnt lgkmcnt(0)" ::: "memory")
#define VMCNT(n)  asm volatile("s_waitcnt vmcnt(" #n ")" ::: "memory")

// ---------------- fp32 -> bf16 bulk convert ---------------------------------
__global__ __launch_bounds__(256) void cvt_kernel(const float* __restrict__ in,
                                                  unsigned short* __restrict__ out,
                                                  int n4) {
    int i = blockIdx.x * 256 + threadIdx.x;
    if (i < n4) {
        float4 v = ((const float4*)in)[i];
        ushort4 o;
        o.x = f2bf(v.x); o.y = f2bf(v.y); o.z = f2bf(v.z); o.w = f2bf(v.w);
        ((ushort4*)out)[i] = o;
    }
}

// pack wq/wk/wv (fp32) -> per-layer [2304][768] bf16
__global__ __launch_bounds__(256) void cvt_qkv_kernel(const float* __restrict__ wq,
                                                      const float* __restrict__ wk,
                                                      const float* __restrict__ wv,
                                                      unsigned short* __restrict__ dst,
                                                      int n4) {
    int i = blockIdx.x * 256 + threadIdx.x;
    if (i >= n4) return;
    const int PER_L = 3 * DM * DM / 4, PER_W = DM * DM / 4;
    int l = i / PER_L;
    int rem = i - l * PER_L;
    int w = rem / PER_W;
    int r2 = rem - w * PER_W;
    const float* src = (w == 0) ? wq : (w == 1) ? wk : wv;
    float4 v = ((const float4*)src)[(size_t)l * PER_W + r2];
    ushort4 o;
    o.x = f2bf(v.x); o.y = f2bf(v.y); o.z = f2bf(v.z); o.w = f2bf(v.w);
    ((ushort4*)dst)[i] = o;
}

__global__ __launch_bounds__(256) void pack_qkv_bias(const float* __restrict__ bq,
                                                     const float* __restrict__ bk,
                                                     const float* __restrict__ bv,
                                                     float* __restrict__ dst) {
    int i = blockIdx.x * 256 + threadIdx.x;   // NL*2304
    if (i >= NL * QKVN) return;
    int l = i / QKVN, c = i - l * QKVN;
    int w = c / DM, cc = c - w * DM;
    const float* src = (w == 0) ? bq : (w == 1) ? bk : bv;
    dst[i] = src[l * DM + cc];
}

// ---------------- embedding + positional encoding --------------------------
__global__ __launch_bounds__(256) void embed_kernel(const int* __restrict__ tok,
                                                    const float* __restrict__ emb,
                                                    const float* __restrict__ pe,
                                                    float* __restrict__ xf,
                                                    unsigned short* __restrict__ xb) {
    int row = blockIdx.x;                 // 0..2047
    int t = tok[row];
    int s = row & (SEQ - 1);
    #pragma unroll
    for (int j = 0; j < 3; ++j) {
        int c = threadIdx.x + j * 256;
        float v = emb[(size_t)t * DM + c] + pe[(size_t)s * DM + c];
        xf[(size_t)row * DM + c] = v;
        xb[(size_t)row * DM + c] = f2bf(v);
    }
}

// ---------------- residual + LayerNorm (writes fp32 + bf16) ----------------
__device__ __forceinline__ float block_sum(float x, float* red) {
    #pragma unroll
    for (int off = 32; off > 0; off >>= 1) x += __shfl_down(x, off);
    int w = threadIdx.x >> 6;
    if ((threadIdx.x & 63) == 0) red[w] = x;
    __syncthreads();
    float t = (red[0] + red[1]) + (red[2] + red[3]);
    __syncthreads();
    return t;
}

__global__ __launch_bounds__(256) void ln_kernel(const float* __restrict__ A,
                                                 const float* __restrict__ Bi,
                                                 const float* __restrict__ sc,
                                                 const float* __restrict__ bi,
                                                 float* __restrict__ xf,
                                                 unsigned short* __restrict__ xb) {
    __shared__ float red[4];
    int row = blockIdx.x, tid = threadIdx.x;
    const float* ap = A + (size_t)row * DM;
    const float* bp = Bi + (size_t)row * DM;
    float v[3], sum = 0.f;
    #pragma unroll
    for (int j = 0; j < 3; ++j) { v[j] = ap[tid + j * 256] + bp[tid + j * 256]; sum += v[j]; }
    sum = block_sum(sum, red);
    float mean = sum * (1.f / DM);
    float vs = 0.f;
    #pragma unroll
    for (int j = 0; j < 3; ++j) { float d = v[j] - mean; vs += d * d; }
    vs = block_sum(vs, red);
    float rstd = rsqrtf(vs * (1.f / DM) + 1e-5f);
    #pragma unroll
    for (int j = 0; j < 3; ++j) {
        int c = tid + j * 256;
        float o = (v[j] - mean) * rstd * sc[c] + bi[c];
        xf[(size_t)row * DM + c] = o;
        xb[(size_t)row * DM + c] = f2bf(o);
    }
}

// ---------------- 128x128-tile bf16 GEMM (layer GEMMs) ---------------------
template <int OUT_BF16>
__global__ __launch_bounds__(256) void gemm128(const unsigned short* __restrict__ A,
                                               const unsigned short* __restrict__ B,
                                               const float* __restrict__ bias,
                                               void* __restrict__ C,
                                               int M, int N, int K, int gx) {
    __shared__ __align__(16) unsigned short As[128 * 64];
    __shared__ __align__(16) unsigned short Bs[128 * 64];
    int bid = blockIdx.x;
    const int nwg = gridDim.x;
    if ((nwg & 7) == 0) {                       // chunked XCD swizzle
        int q = nwg >> 3;
        bid = (bid & 7) * q + (bid >> 3);
    }
    const int bx = bid % gx, by = bid / gx;
    const int m0 = bx * 128, n0 = by * 128;
    const int tid = threadIdx.x, lane = tid & 63, wid = tid >> 6;
    const int wm = wid >> 1, wn = wid & 1;      // wave -> 64x64 quadrant
    const int lr = lane & 15, lq = lane >> 4;

    const int sr = wid * 32 + (lane >> 3);
    const int sch = lane & 7;
    const int scs = sch ^ (sr & 7);
    const unsigned short* aP[4];
    const unsigned short* bP[4];
    unsigned short* aL[4];
    unsigned short* bL[4];
    #pragma unroll
    for (int i = 0; i < 4; ++i) {
        int r = sr + i * 8;
        aP[i] = A + (size_t)(m0 + r) * K + scs * 8;
        int br = n0 + r; if (br >= N) br = N - 1;
        bP[i] = B + (size_t)br * K + scs * 8;
        aL[i] = &As[r * 64 + sch * 8];
        bL[i] = &Bs[r * 64 + sch * 8];
    }

    f32x4 acc[4][4] = {};

    for (int k0 = 0; k0 < K; k0 += 64) {
        #pragma unroll
        for (int i = 0; i < 4; ++i) GLOAD16(aP[i] + k0, aL[i]);
        #pragma unroll
        for (int i = 0; i < 4; ++i) GLOAD16(bP[i] + k0, bL[i]);
        __syncthreads();
        #pragma unroll
        for (int kk = 0; kk < 2; ++kk) {
            short8 a[4], b[4];
            #pragma unroll
            for (int i = 0; i < 4; ++i) {
                int ar = wm * 64 + i * 16 + lr;
                a[i] = *reinterpret_cast<const short8*>(
                    &As[ar * 64 + (((kk * 4 + lq) ^ (ar & 7)) * 8)]);
                int br = wn * 64 + i * 16 + lr;
                b[i] = *reinterpret_cast<const short8*>(
                    &Bs[br * 64 + (((kk * 4 + lq) ^ (br & 7)) * 8)]);
            }
            #pragma unroll
            for (int i = 0; i < 4; ++i)
                #pragma unroll
                for (int j = 0; j < 4; ++j)
                    acc[i][j] = __builtin_amdgcn_mfma_f32_16x16x32_bf16(a[i], b[j], acc[i][j], 0, 0, 0);
        }
        __syncthreads();
    }
    #pragma unroll
    for (int i = 0; i < 4; ++i) {
        int row = m0 + wm * 64 + i * 16 + lq * 4;
        #pragma unroll
        for (int j = 0; j < 4; ++j) {
            int col = n0 + wn * 64 + j * 16 + lr;
            if (col < N) {
                float bv = bias[col];
                #pragma unroll
                for (int r = 0; r < 4; ++r) {
                    float v = acc[i][j][r] + bv;
                    if (OUT_BF16) ((unsigned short*)C)[(size_t)(row + r) * N + col] = f2bf(v);
                    else          ((float*)C)[(size_t)(row + r) * N + col] = v;
                }
            }
        }
    }
}

// ---------------- 256x256 8-phase GEMM (unembed, K=768 fixed) --------------
// m201-style schedule. Waves 2(M)x4(N), per-wave 128x64. Per K-tile, 4 phases
// (one C-quadrant each). Slots: A0/A1 = A-row classes {wm*128+ih*64+[0,64)},
// B0/B1 = B-row classes {wn*64+jh*32+[0,32)}. LDS reads: A0,B0 @q0; B1 @q1;
// A1 @q2 (regs persist). Frees: A0,B0 after q0; B1 after q1; A1 after q3.
// Stages (into just-freed slots, one half-tile = 2 loads/thread per phase):
//   q0: A1(t+1)  q1: B1(t+1)  q2: A0(t+2)  q3: B0(t+2)
// vmcnt: q0-end (6) covers B1(t)/A1(t); q3-end (8) covers A0/B0(t+1).
// Tail: t=NT-2 q3 -> vmcnt(4); t=NT-1 q0-end -> vmcnt(0). Full unroll folds
// all conditions and waitcnt literals.
template <int OUT_BF16>
__global__ __launch_bounds__(512, 2) void gemm256_8p(const unsigned short* __restrict__ A,
                                                     const unsigned short* __restrict__ B,
                                                     const float* __restrict__ bias,
                                                     void* __restrict__ C,
                                                     int N, int gx) {
    constexpr int K = 768;
    constexpr int NT = K / 64;                  // 12
    __shared__ __align__(16) unsigned short As[2][256 * 64];
    __shared__ __align__(16) unsigned short Bs[2][256 * 64];
    int bid = blockIdx.x;
    const int nwg = gridDim.x;
    { int q = nwg >> 3; bid = (bid & 7) * q + (bid >> 3); }   // nwg%8==0
    const int bx = bid % gx, by = bid / gx;
    const int m0 = bx * 256, n0 = by * 256;
    const int tid = threadIdx.x, lane = tid & 63, wid = tid >> 6;
    const int wm = wid >> 2, wn = wid & 3;      // 2x4 wave grid
    const int lr = lane & 15, lq = lane >> 4;

    const int sr = tid >> 3;                    // 0..63
    const int sch = tid & 7;
    const int scs = sch ^ (sr & 7);             // inverse-swizzled source chunk

    const unsigned short* aB = A + (size_t)(m0 + sr) * K + scs * 8;
    const unsigned short* bB[2][2];
    #pragma unroll
    for (int jh = 0; jh < 2; ++jh)
        #pragma unroll
        for (int i = 0; i < 2; ++i) {
            int row = ((sr >> 5) + 2 * i) * 64 + jh * 32 + (sr & 31);
            int br = n0 + row; if (br >= N) br = N - 1;
            bB[jh][i] = B + (size_t)br * K + scs * 8;
        }

#define STAGE_A(t, c, ih)                                                      \
    do { _Pragma("unroll")                                                     \
        for (int _i = 0; _i < 2; ++_i) {                                       \
            int _row = _i * 128 + (ih) * 64 + sr;                              \
            GLOAD16(aB + (size_t)(_i * 128 + (ih) * 64) * K + (t) * 64,        \
                    &As[c][_row * 64 + sch * 8]);                              \
        } } while (0)
#define STAGE_B(t, c, jh)                                                      \
    do { _Pragma("unroll")                                                     \
        for (int _i = 0; _i < 2; ++_i) {                                       \
            int _row = ((sr >> 5) + 2 * _i) * 64 + (jh) * 32 + (sr & 31);      \
            GLOAD16(bB[jh][_i] + (t) * 64,                                     \
                    &Bs[c][_row * 64 + sch * 8]);                              \
        } } while (0)
#define LDA(D, c, ih)                                                          \
    do { _Pragma("unroll")                                                     \
        for (int _i = 0; _i < 4; ++_i) {                                       \
            int _ar = wm * 128 + (ih) * 64 + _i * 16 + lr;                     \
            _Pragma("unroll")                                                  \
            for (int _kk = 0; _kk < 2; ++_kk)                                  \
                D[_i][_kk] = *reinterpret_cast<const short8*>(                 \
                    &As[c][_ar * 64 + (((_kk * 4 + lq) ^ (_ar & 7)) * 8)]);    \
        } } while (0)
#define LDB(D, c, jh)                                                          \
    do { _Pragma("unroll")                                                     \
        for (int _j = 0; _j < 2; ++_j) {                                       \
            int _br = wn * 64 + (jh) * 32 + _j * 16 + lr;                      \
            _Pragma("unroll")                                                  \
            for (int _kk = 0; _kk < 2; ++_kk)                                  \
                D[_j][_kk] = *reinterpret_cast<const short8*>(                 \
                    &Bs[c][_br * 64 + (((_kk * 4 + lq) ^ (_br & 7)) * 8)]);    \
        } } while (0)
#define MFMA16(BI, BJ, AF, BF)                                                 \
    do { _Pragma("unroll")                                                     \
        for (int _i = 0; _i < 4; ++_i) {                                       \
            _Pragma("unroll")                                                  \
            for (int _j = 0; _j < 2; ++_j) {                                   \
                acc[(BI) + _i][(BJ) + _j] = __builtin_amdgcn_mfma_f32_16x16x32_bf16( \
                    AF[_i][0], BF[_j][0], acc[(BI) + _i][(BJ) + _j], 0, 0, 0); \
                acc[(BI) + _i][(BJ) + _j] = __builtin_amdgcn_mfma_f32_16x16x32_bf16( \
                    AF[_i][1], BF[_j][1], acc[(BI) + _i][(BJ) + _j], 0, 0, 0); \
            }                                                                  \
        } } while (0)

    short8 afr[4][2], b0f[2][2], b1f[2][2];
    f32x4 acc[8][4] = {};

    // prologue: tiles 0 and 1 fully staged (8 + 8 loads/thread)
    STAGE_A(0, 0, 0); STAGE_B(0, 0, 0); STAGE_A(0, 0, 1); STAGE_B(0, 0, 1);
    STAGE_A(1, 1, 0); STAGE_B(1, 1, 0); STAGE_A(1, 1, 1); STAGE_B(1, 1, 1);
    VMCNT(8);                                   // tile0's 8 loads done
    BARRIER();

    #pragma unroll
    for (int t = 0; t < NT; ++t) {
        const int c = t & 1;
        // ---- phase 0: quad (ih=0, jh=0) -----------------------------------
        LDA(afr, c, 0);
        LDB(b0f, c, 0);
        if (t >= 1 && t + 1 < NT) STAGE_A(t + 1, c ^ 1, 1);
        BARRIER();
        LGKM0();
        __builtin_amdgcn_s_setprio(1);
        MFMA16(0, 0, afr, b0f);
        __builtin_amdgcn_s_setprio(0);
        if (t == NT - 1) { VMCNT(0); } else { VMCNT(6); }
        BARRIER();
        // ---- phase 1: quad (0, 1) -----------------------------------------
        LDB(b1f, c, 1);
        if (t >= 1 && t + 1 < NT) STAGE_B(t + 1, c ^ 1, 1);
        BARRIER();
        LGKM0();
        __builtin_amdgcn_s_setprio(1);
        MFMA16(0, 2, afr, b1f);
        __builtin_amdgcn_s_setprio(0);
        BARRIER();
        // ---- phase 2: quad (1, 0) -----------------------------------------
        LDA(afr, c, 1);
        if (t + 2 < NT) STAGE_A(t + 2, c, 0);
        BARRIER();
        LGKM0();
        __builtin_amdgcn_s_setprio(1);
        MFMA16(4, 0, afr, b0f);
        __builtin_amdgcn_s_setprio(0);
        BARRIER();
        // ---- phase 3: quad (1, 1) -----------------------------------------
        if (t + 2 < NT) STAGE_B(t + 2, c, 0);
        BARRIER();
        LGKM0();
        __builtin_amdgcn_s_setprio(1);
        MFMA16(4, 2, afr, b1f);
        __builtin_amdgcn_s_setprio(0);
        if (t + 2 < NT) { VMCNT(8); }
        else if (t + 2 == NT) { VMCNT(4); }
        BARRIER();
    }

    #pragma unroll
    for (int i = 0; i < 8; ++i) {
        int row = m0 + wm * 128 + i * 16 + lq * 4;
        #pragma unroll
        for (int j = 0; j < 4; ++j) {
            int col = n0 + wn * 64 + j * 16 + lr;
            if (col < N) {
                float bv = bias[col];
                #pragma unroll
                for (int r = 0; r < 4; ++r) {
                    float v = acc[i][j][r] + bv;
                    if (OUT_BF16)
                        ((unsigned short*)C)[(size_t)(row + r) * N + col] = f2bf(v);
                    else
                        __builtin_nontemporal_store(
                            v, &((float*)C)[(size_t)(row + r) * N + col]);
                }
            }
        }
    }
#undef STAGE_A
#undef STAGE_B
#undef LDA
#undef LDB
#undef MFMA16
}

// ---------------- flash attention (causal), bf16 MFMA ----------------------
__global__ __launch_bounds__(256) void attn_kernel(const unsigned short* __restrict__ Q,
                                                   const unsigned short* __restrict__ K,
                                                   const unsigned short* __restrict__ V,
                                                   int ld,
                                                   float* __restrict__ O) {
    __shared__ __align__(16) unsigned short Ks[64 * 64];
    __shared__ __align__(16) unsigned short Vs[64 * 64];     // transposed [d][kv]
    __shared__ __align__(16) unsigned short Ps[4][16 * 64];  // per-wave P tile
    const int qb = blockIdx.x;
    const int bh = blockIdx.y;
    const int b = bh / NH, h = bh % NH;
    const int tid = threadIdx.x, lane = tid & 63, w = tid >> 6;
    const int lr = lane & 15, lq = lane >> 4;
    const int wq0 = qb * 64 + w * 16;
    const size_t base = (size_t)b * SEQ * ld + h * DH;
    const size_t obase = (size_t)b * SEQ * DM + h * DH;

    short8 qf[2];
    {
        const unsigned short* qp = Q + base + (size_t)(wq0 + lr) * ld + lq * 8;
        qf[0] = *reinterpret_cast<const short8*>(qp);
        qf[1] = *reinterpret_cast<const short8*>(qp + 32);
    }
    f32x4 o_acc[4] = {};
    float mrow[4], lrow[4];
    #pragma unroll
    for (int r = 0; r < 4; ++r) { mrow[r] = -1e30f; lrow[r] = 0.f; }

    const int srow = tid >> 3, scol = (tid & 7) * 8;
    for (int t = 0; t <= qb; ++t) {
        const int kv0 = t * 64;
        #pragma unroll
        for (int rr = 0; rr < 2; ++rr) {
            int row = rr * 32 + srow;
            {
                const unsigned short* kp = K + base + (size_t)(kv0 + row) * ld + scol;
                short8 v = *reinterpret_cast<const short8*>(kp);
                *reinterpret_cast<short8*>(&Ks[(row * 64 + scol) ^ ((row & 7) << 3)]) = v;
            }
            {
                const unsigned short* vp = V + base + (size_t)(kv0 + row) * ld + scol;
                short8 v = *reinterpret_cast<const short8*>(vp);
                #pragma unroll
                for (int j = 0; j < 8; ++j) {
                    int d = scol + j;
                    Vs[(d * 64 + row) ^ ((d & 7) << 3)] = (unsigned short)v[j];
                }
            }
        }
        __syncthreads();
        if (kv0 <= wq0 + 15) {
            f32x4 s[4];
            #pragma unroll
            for (int n = 0; n < 4; ++n) {
                int br = n * 16 + lr;
                short8 b0 = *reinterpret_cast<const short8*>(&Ks[(br * 64 + lq * 8) ^ ((br & 7) << 3)]);
                short8 b1 = *reinterpret_cast<const short8*>(&Ks[(br * 64 + 32 + lq * 8) ^ ((br & 7) << 3)]);
                f32x4 z = {};
                z = __builtin_amdgcn_mfma_f32_16x16x32_bf16(qf[0], b0, z, 0, 0, 0);
                z = __builtin_amdgcn_mfma_f32_16x16x32_bf16(qf[1], b1, z, 0, 0, 0);
                s[n] = z;
            }
            const bool diag = (t == qb);
            #pragma unroll
            for (int n = 0; n < 4; ++n)
                #pragma unroll
                for (int r = 0; r < 4; ++r) {
                    float v = s[n][r] * 0.125f;
                    if (diag) {
                        int rg = wq0 + lq * 4 + r;
                        int cg = kv0 + n * 16 + lr;
                        if (cg > rg) v = -1e30f;
                    }
                    s[n][r] = v;
                }
            float f[4];
            #pragma unroll
            for (int r = 0; r < 4; ++r) {
                float mx = fmaxf(fmaxf(s[0][r], s[1][r]), fmaxf(s[2][r], s[3][r]));
                #pragma unroll
                for (int off = 1; off < 16; off <<= 1) mx = fmaxf(mx, __shfl_xor(mx, off));
                float mn = fmaxf(mrow[r], mx);
                f[r] = exp2f((mrow[r] - mn) * 1.44269504f);
                mrow[r] = mn;
            }
            #pragma unroll
            for (int n = 0; n < 4; ++n)
                #pragma unroll
                for (int r = 0; r < 4; ++r)
                    s[n][r] = exp2f((s[n][r] - mrow[r]) * 1.44269504f);
            #pragma unroll
            for (int r = 0; r < 4; ++r) {
                float ls = ((s[0][r] + s[1][r]) + (s[2][r] + s[3][r]));
                #pragma unroll
                for (int off = 1; off < 16; off <<= 1) ls += __shfl_xor(ls, off);
                lrow[r] = lrow[r] * f[r] + ls;
            }
            #pragma unroll
            for (int n = 0; n < 4; ++n)
                #pragma unroll
                for (int r = 0; r < 4; ++r) {
                    int pr = lq * 4 + r, pc = n * 16 + lr;
                    Ps[w][(pr * 64 + pc) ^ ((pr & 7) << 3)] = f2bf(s[n][r]);
                }
            #pragma unroll
            for (int n = 0; n < 4; ++n)
                #pragma unroll
                for (int r = 0; r < 4; ++r) o_acc[n][r] *= f[r];
            #pragma unroll
            for (int kk = 0; kk < 2; ++kk) {
                short8 pa = *reinterpret_cast<const short8*>(
                    &Ps[w][(lr * 64 + kk * 32 + lq * 8) ^ ((lr & 7) << 3)]);
                #pragma unroll
                for (int n = 0; n < 4; ++n) {
                    int vr = n * 16 + lr;
                    short8 bv = *reinterpret_cast<const short8*>(
                        &Vs[(vr * 64 + kk * 32 + lq * 8) ^ ((vr & 7) << 3)]);
                    o_acc[n] = __builtin_amdgcn_mfma_f32_16x16x32_bf16(pa, bv, o_acc[n], 0, 0, 0);
                }
            }
        }
        __syncthreads();
    }
    #pragma unroll
    for (int r = 0; r < 4; ++r) {
        float inv = 1.f / lrow[r];
        int row = wq0 + lq * 4 + r;
        #pragma unroll
        for (int n = 0; n < 4; ++n)
            O[obase + (size_t)row * DM + n * 16 + lr] = o_acc[n][r] * inv;
    }
}

// ---------------------------------------------------------------------------
extern "C" void kernel_launch(void* const* d_in, const int* in_sizes, int n_in,
                              void* d_out, int out_size, void* d_ws, size_t ws_size,
                              hipStream_t stream) {
    const int*   tokens   = (const int*)d_in[0];
    const float* embed    = (const float*)d_in[1];
    const float* pe       = (const float*)d_in[2];
    const float* wq_w     = (const float*)d_in[3];
    const float* wq_b     = (const float*)d_in[4];
    const float* wk_w     = (const float*)d_in[5];
    const float* wk_b     = (const float*)d_in[6];
    const float* wv_w     = (const float*)d_in[7];
    const float* wv_b     = (const float*)d_in[8];
    const float* lin_w    = (const float*)d_in[9];
    const float* lin_b    = (const float*)d_in[10];
    const float* n1_s     = (const float*)d_in[11];
    const float* n1_b     = (const float*)d_in[12];
    const float* n2_s     = (const float*)d_in[13];
    const float* n2_b     = (const float*)d_in[14];
    const float* unemb_w  = (const float*)d_in[15];
    const float* unemb_b  = (const float*)d_in[16];

    char* ws = (char*)d_ws;
    size_t off = 0;
    auto carve = [&](size_t bytes) { char* p = ws + off; off += (bytes + 255) & ~(size_t)255; return p; };
    float*          xf     = (float*)carve((size_t)ROWS * DM * 4);
    float*          yb     = (float*)carve((size_t)ROWS * DM * 4);
    unsigned short* xb     = (unsigned short*)carve((size_t)ROWS * DM * 2);
    unsigned short* qkv    = (unsigned short*)carve((size_t)ROWS * QKVN * 2);
    unsigned short* wqkv_h = (unsigned short*)carve((size_t)NL * QKVN * DM * 2);
    unsigned short* lin_h  = (unsigned short*)carve((size_t)NL * DM * DM * 2);
    unsigned short* ue_h   = (unsigned short*)carve((size_t)VOCAB * DM * 2);
    float*          qkvb   = (float*)carve((size_t)NL * QKVN * 4);

    {
        int nq4 = NL * QKVN * DM / 4;
        cvt_qkv_kernel<<<(nq4 + 255) / 256, 256, 0, stream>>>(wq_w, wk_w, wv_w, wqkv_h, nq4);
        int nl4 = NL * DM * DM / 4;
        cvt_kernel<<<(nl4 + 255) / 256, 256, 0, stream>>>(lin_w, lin_h, nl4);
        int nu4 = VOCAB * DM / 4;
        cvt_kernel<<<(nu4 + 255) / 256, 256, 0, stream>>>(unemb_w, ue_h, nu4);
        pack_qkv_bias<<<(NL * QKVN + 255) / 256, 256, 0, stream>>>(wq_b, wk_b, wv_b, qkvb);
    }
    embed_kernel<<<ROWS, 256, 0, stream>>>(tokens, embed, pe, xf, xb);

    const int gx = ROWS / 128;   // 16 M-blocks (128-tile)
    for (int l = 0; l < NL; ++l) {
        gemm128<1><<<gx * (QKVN / 128), 256, 0, stream>>>(
            xb, wqkv_h + (size_t)l * QKVN * DM, qkvb + l * QKVN, qkv,
            ROWS, QKVN, DM, gx);
        attn_kernel<<<dim3(SEQ / 64, BATCH * NH), 256, 0, stream>>>(
            qkv, qkv + DM, qkv + 2 * DM, QKVN, yb);
        ln_kernel<<<ROWS, 256, 0, stream>>>(xf, yb, n1_s + l * DM, n1_b + l * DM, xf, xb);
        gemm128<0><<<gx * (DM / 128), 256, 0, stream>>>(
            xb, lin_h + (size_t)l * DM * DM, lin_b + l * DM, yb,
            ROWS, DM, DM, gx);
        ln_kernel<<<ROWS, 256, 0, stream>>>(xf, yb, n2_s + l * DM, n2_b + l * DM, xf, xb);
    }
    // unembed: [2048,768] x [50257,768]^T -> d_out fp32, 8-phase 256 GEMM
    const int gxu = ROWS / 256;                 // 8
    const int gyu = (VOCAB + 255) / 256;        // 197
    gemm256_8p<0><<<gxu * gyu, 512, 0, stream>>>(
        xb, ue_h, unemb_b, (float*)d_out, VOCAB, gxu);
}

// Round 5
// 840.328 us; speedup vs baseline: 1.1881x; 1.1881x over previous
//
#include <hip/hip_runtime.h>
#include <hip/hip_bf16.h>

// ---------------------------------------------------------------------------
// BYOGPT forward: embed+PE -> 4x[QKV proj, flash-attn, LN, lin, LN] -> unembed
// B=2 S=1024 D=768 H=12 Dh=64 V=50257. bf16 MFMA GEMMs, fp32 residual/LN.
// R5: unembed 8-phase GEMM fixed: ROLLED main loop (R4's full unroll made a
//     ~3000-inst body -> I-fetch bound, all counters low) and PLAIN stores
//     (R4's nontemporal stores inflated HBM writes 417->720 MB).
// ---------------------------------------------------------------------------

#define VOCAB 50257
#define DM 768
#define NL 4
#define NH 12
#define DH 64
#define SEQ 1024
#define BATCH 2
#define ROWS (BATCH * SEQ)   // 2048
#define QKVN (3 * DM)        // 2304

typedef __attribute__((ext_vector_type(8))) short short8;
typedef __attribute__((ext_vector_type(4))) float f32x4;

__device__ __forceinline__ unsigned short f2bf(float f) {
    union { float f; unsigned u; } v; v.f = f;
    unsigned r = v.u + 0x7FFFu + ((v.u >> 16) & 1u);   // RNE
    return (unsigned short)(r >> 16);
}

#define GLOAD16(gp, lp)                                                        \
    __builtin_amdgcn_global_load_lds(                                          \
        (const __attribute__((address_space(1))) unsigned int*)(gp),           \
        (__attribute__((address_space(3))) unsigned int*)(lp), 16, 0, 0)

#define BARRIER() asm volatile("s_barrier" ::: "memory")
#define LGKM0()   asm volatile("s_waitcnt lgkmcnt(0)" ::: "memory")
#define VMCNT(n)  asm volatile("s_waitcnt vmcnt(" #n ")" ::: "memory")

// ---------------- fp32 -> bf16 bulk convert ---------------------------------
__global__ __launch_bounds__(256) void cvt_kernel(const float* __restrict__ in,
                                                  unsigned short* __restrict__ out,
                                                  int n4) {
    int i = blockIdx.x * 256 + threadIdx.x;
    if (i < n4) {
        float4 v = ((const float4*)in)[i];
        ushort4 o;
        o.x = f2bf(v.x); o.y = f2bf(v.y); o.z = f2bf(v.z); o.w = f2bf(v.w);
        ((ushort4*)out)[i] = o;
    }
}

// pack wq/wk/wv (fp32) -> per-layer [2304][768] bf16
__global__ __launch_bounds__(256) void cvt_qkv_kernel(const float* __restrict__ wq,
                                                      const float* __restrict__ wk,
                                                      const float* __restrict__ wv,
                                                      unsigned short* __restrict__ dst,
                                                      int n4) {
    int i = blockIdx.x * 256 + threadIdx.x;
    if (i >= n4) return;
    const int PER_L = 3 * DM * DM / 4, PER_W = DM * DM / 4;
    int l = i / PER_L;
    int rem = i - l * PER_L;
    int w = rem / PER_W;
    int r2 = rem - w * PER_W;
    const float* src = (w == 0) ? wq : (w == 1) ? wk : wv;
    float4 v = ((const float4*)src)[(size_t)l * PER_W + r2];
    ushort4 o;
    o.x = f2bf(v.x); o.y = f2bf(v.y); o.z = f2bf(v.z); o.w = f2bf(v.w);
    ((ushort4*)dst)[i] = o;
}

__global__ __launch_bounds__(256) void pack_qkv_bias(const float* __restrict__ bq,
                                                     const float* __restrict__ bk,
                                                     const float* __restrict__ bv,
                                                     float* __restrict__ dst) {
    int i = blockIdx.x * 256 + threadIdx.x;   // NL*2304
    if (i >= NL * QKVN) return;
    int l = i / QKVN, c = i - l * QKVN;
    int w = c / DM, cc = c - w * DM;
    const float* src = (w == 0) ? bq : (w == 1) ? bk : bv;
    dst[i] = src[l * DM + cc];
}

// ---------------- embedding + positional encoding --------------------------
__global__ __launch_bounds__(256) void embed_kernel(const int* __restrict__ tok,
                                                    const float* __restrict__ emb,
                                                    const float* __restrict__ pe,
                                                    float* __restrict__ xf,
                                                    unsigned short* __restrict__ xb) {
    int row = blockIdx.x;                 // 0..2047
    int t = tok[row];
    int s = row & (SEQ - 1);
    #pragma unroll
    for (int j = 0; j < 3; ++j) {
        int c = threadIdx.x + j * 256;
        float v = emb[(size_t)t * DM + c] + pe[(size_t)s * DM + c];
        xf[(size_t)row * DM + c] = v;
        xb[(size_t)row * DM + c] = f2bf(v);
    }
}

// ---------------- residual + LayerNorm (writes fp32 + bf16) ----------------
__device__ __forceinline__ float block_sum(float x, float* red) {
    #pragma unroll
    for (int off = 32; off > 0; off >>= 1) x += __shfl_down(x, off);
    int w = threadIdx.x >> 6;
    if ((threadIdx.x & 63) == 0) red[w] = x;
    __syncthreads();
    float t = (red[0] + red[1]) + (red[2] + red[3]);
    __syncthreads();
    return t;
}

__global__ __launch_bounds__(256) void ln_kernel(const float* __restrict__ A,
                                                 const float* __restrict__ Bi,
                                                 const float* __restrict__ sc,
                                                 const float* __restrict__ bi,
                                                 float* __restrict__ xf,
                                                 unsigned short* __restrict__ xb) {
    __shared__ float red[4];
    int row = blockIdx.x, tid = threadIdx.x;
    const float* ap = A + (size_t)row * DM;
    const float* bp = Bi + (size_t)row * DM;
    float v[3], sum = 0.f;
    #pragma unroll
    for (int j = 0; j < 3; ++j) { v[j] = ap[tid + j * 256] + bp[tid + j * 256]; sum += v[j]; }
    sum = block_sum(sum, red);
    float mean = sum * (1.f / DM);
    float vs = 0.f;
    #pragma unroll
    for (int j = 0; j < 3; ++j) { float d = v[j] - mean; vs += d * d; }
    vs = block_sum(vs, red);
    float rstd = rsqrtf(vs * (1.f / DM) + 1e-5f);
    #pragma unroll
    for (int j = 0; j < 3; ++j) {
        int c = tid + j * 256;
        float o = (v[j] - mean) * rstd * sc[c] + bi[c];
        xf[(size_t)row * DM + c] = o;
        xb[(size_t)row * DM + c] = f2bf(o);
    }
}

// ---------------- 128x128-tile bf16 GEMM (layer GEMMs) ---------------------
template <int OUT_BF16>
__global__ __launch_bounds__(256) void gemm128(const unsigned short* __restrict__ A,
                                               const unsigned short* __restrict__ B,
                                               const float* __restrict__ bias,
                                               void* __restrict__ C,
                                               int M, int N, int K, int gx) {
    __shared__ __align__(16) unsigned short As[128 * 64];
    __shared__ __align__(16) unsigned short Bs[128 * 64];
    int bid = blockIdx.x;
    const int nwg = gridDim.x;
    if ((nwg & 7) == 0) {                       // chunked XCD swizzle
        int q = nwg >> 3;
        bid = (bid & 7) * q + (bid >> 3);
    }
    const int bx = bid % gx, by = bid / gx;
    const int m0 = bx * 128, n0 = by * 128;
    const int tid = threadIdx.x, lane = tid & 63, wid = tid >> 6;
    const int wm = wid >> 1, wn = wid & 1;      // wave -> 64x64 quadrant
    const int lr = lane & 15, lq = lane >> 4;

    const int sr = wid * 32 + (lane >> 3);
    const int sch = lane & 7;
    const int scs = sch ^ (sr & 7);
    const unsigned short* aP[4];
    const unsigned short* bP[4];
    unsigned short* aL[4];
    unsigned short* bL[4];
    #pragma unroll
    for (int i = 0; i < 4; ++i) {
        int r = sr + i * 8;
        aP[i] = A + (size_t)(m0 + r) * K + scs * 8;
        int br = n0 + r; if (br >= N) br = N - 1;
        bP[i] = B + (size_t)br * K + scs * 8;
        aL[i] = &As[r * 64 + sch * 8];
        bL[i] = &Bs[r * 64 + sch * 8];
    }

    f32x4 acc[4][4] = {};

    for (int k0 = 0; k0 < K; k0 += 64) {
        #pragma unroll
        for (int i = 0; i < 4; ++i) GLOAD16(aP[i] + k0, aL[i]);
        #pragma unroll
        for (int i = 0; i < 4; ++i) GLOAD16(bP[i] + k0, bL[i]);
        __syncthreads();
        #pragma unroll
        for (int kk = 0; kk < 2; ++kk) {
            short8 a[4], b[4];
            #pragma unroll
            for (int i = 0; i < 4; ++i) {
                int ar = wm * 64 + i * 16 + lr;
                a[i] = *reinterpret_cast<const short8*>(
                    &As[ar * 64 + (((kk * 4 + lq) ^ (ar & 7)) * 8)]);
                int br = wn * 64 + i * 16 + lr;
                b[i] = *reinterpret_cast<const short8*>(
                    &Bs[br * 64 + (((kk * 4 + lq) ^ (br & 7)) * 8)]);
            }
            #pragma unroll
            for (int i = 0; i < 4; ++i)
                #pragma unroll
                for (int j = 0; j < 4; ++j)
                    acc[i][j] = __builtin_amdgcn_mfma_f32_16x16x32_bf16(a[i], b[j], acc[i][j], 0, 0, 0);
        }
        __syncthreads();
    }
    #pragma unroll
    for (int i = 0; i < 4; ++i) {
        int row = m0 + wm * 64 + i * 16 + lq * 4;
        #pragma unroll
        for (int j = 0; j < 4; ++j) {
            int col = n0 + wn * 64 + j * 16 + lr;
            if (col < N) {
                float bv = bias[col];
                #pragma unroll
                for (int r = 0; r < 4; ++r) {
                    float v = acc[i][j][r] + bv;
                    if (OUT_BF16) ((unsigned short*)C)[(size_t)(row + r) * N + col] = f2bf(v);
                    else          ((float*)C)[(size_t)(row + r) * N + col] = v;
                }
            }
        }
    }
}

// ---------------- 256x256 8-phase GEMM (unembed, K=768 fixed) --------------
// m201-style schedule, ROLLED main loop. Waves 2(M)x4(N), per-wave 128x64.
// Per K-tile 4 phases (one C-quadrant each). LDS reads: A0,B0 @q0; B1 @q1;
// A1 @q2 (regs persist). Stages into just-freed slots:
//   q0: A1(t+1)  q1: B1(t+1)  q2: A0(t+2)  q3: B0(t+2)
// vmcnt: q0-end 6 (covers B1/A1 of t); q3-end 8 (covers A0/B0 of t+1).
// Tail: t=NT-2 q3 -> vmcnt(4); t=NT-1 q0-end -> vmcnt(0). vmcnt(N) with
// fewer than N outstanding passes trivially, so fixed literals stay safe.
template <int OUT_BF16>
__global__ __launch_bounds__(512, 2) void gemm256_8p(const unsigned short* __restrict__ A,
                                                     const unsigned short* __restrict__ B,
                                                     const float* __restrict__ bias,
                                                     void* __restrict__ C,
                                                     int N, int gx) {
    constexpr int K = 768;
    constexpr int NT = K / 64;                  // 12
    __shared__ __align__(16) unsigned short As[2][256 * 64];
    __shared__ __align__(16) unsigned short Bs[2][256 * 64];
    int bid = blockIdx.x;
    const int nwg = gridDim.x;
    { int q = nwg >> 3; bid = (bid & 7) * q + (bid >> 3); }   // nwg%8==0
    const int bx = bid % gx, by = bid / gx;
    const int m0 = bx * 256, n0 = by * 256;
    const int tid = threadIdx.x, lane = tid & 63, wid = tid >> 6;
    const int wm = wid >> 2, wn = wid & 3;      // 2x4 wave grid
    const int lr = lane & 15, lq = lane >> 4;

    const int sr = tid >> 3;                    // 0..63
    const int sch = tid & 7;
    const int scs = sch ^ (sr & 7);             // inverse-swizzled source chunk

    const unsigned short* aB = A + (size_t)(m0 + sr) * K + scs * 8;
    const unsigned short* bB[2][2];
    #pragma unroll
    for (int jh = 0; jh < 2; ++jh)
        #pragma unroll
        for (int i = 0; i < 2; ++i) {
            int row = ((sr >> 5) + 2 * i) * 64 + jh * 32 + (sr & 31);
            int br = n0 + row; if (br >= N) br = N - 1;
            bB[jh][i] = B + (size_t)br * K + scs * 8;
        }

#define STAGE_A(t, c, ih)                                                      \
    do { _Pragma("unroll")                                                     \
        for (int _i = 0; _i < 2; ++_i) {                                       \
            int _row = _i * 128 + (ih) * 64 + sr;                              \
            GLOAD16(aB + (size_t)(_i * 128 + (ih) * 64) * K + (t) * 64,        \
                    &As[c][_row * 64 + sch * 8]);                              \
        } } while (0)
#define STAGE_B(t, c, jh)                                                      \
    do { _Pragma("unroll")                                                     \
        for (int _i = 0; _i < 2; ++_i) {                                       \
            int _row = ((sr >> 5) + 2 * _i) * 64 + (jh) * 32 + (sr & 31);      \
            GLOAD16(bB[jh][_i] + (t) * 64,                                     \
                    &Bs[c][_row * 64 + sch * 8]);                              \
        } } while (0)
#define LDA(D, c, ih)                                                          \
    do { _Pragma("unroll")                                                     \
        for (int _i = 0; _i < 4; ++_i) {                                       \
            int _ar = wm * 128 + (ih) * 64 + _i * 16 + lr;                     \
            _Pragma("unroll")                                                  \
            for (int _kk = 0; _kk < 2; ++_kk)                                  \
                D[_i][_kk] = *reinterpret_cast<const short8*>(                 \
                    &As[c][_ar * 64 + (((_kk * 4 + lq) ^ (_ar & 7)) * 8)]);    \
        } } while (0)
#define LDB(D, c, jh)                                                          \
    do { _Pragma("unroll")                                                     \
        for (int _j = 0; _j < 2; ++_j) {                                       \
            int _br = wn * 64 + (jh) * 32 + _j * 16 + lr;                      \
            _Pragma("unroll")                                                  \
            for (int _kk = 0; _kk < 2; ++_kk)                                  \
                D[_j][_kk] = *reinterpret_cast<const short8*>(                 \
                    &Bs[c][_br * 64 + (((_kk * 4 + lq) ^ (_br & 7)) * 8)]);    \
        } } while (0)
#define MFMA16(BI, BJ, AF, BF)                                                 \
    do { _Pragma("unroll")                                                     \
        for (int _i = 0; _i < 4; ++_i) {                                       \
            _Pragma("unroll")                                                  \
            for (int _j = 0; _j < 2; ++_j) {                                   \
                acc[(BI) + _i][(BJ) + _j] = __builtin_amdgcn_mfma_f32_16x16x32_bf16( \
                    AF[_i][0], BF[_j][0], acc[(BI) + _i][(BJ) + _j], 0, 0, 0); \
                acc[(BI) + _i][(BJ) + _j] = __builtin_amdgcn_mfma_f32_16x16x32_bf16( \
                    AF[_i][1], BF[_j][1], acc[(BI) + _i][(BJ) + _j], 0, 0, 0); \
            }                                                                  \
        } } while (0)

    short8 afr[4][2], b0f[2][2], b1f[2][2];
    f32x4 acc[8][4] = {};

    // prologue: tiles 0 and 1 fully staged (8 + 8 loads/thread)
    STAGE_A(0, 0, 0); STAGE_B(0, 0, 0); STAGE_A(0, 0, 1); STAGE_B(0, 0, 1);
    STAGE_A(1, 1, 0); STAGE_B(1, 1, 0); STAGE_A(1, 1, 1); STAGE_B(1, 1, 1);
    VMCNT(8);                                   // tile0's 8 loads done
    BARRIER();

    #pragma unroll 1
    for (int t = 0; t < NT; ++t) {
        const int c = t & 1;
        const bool sN1 = (t >= 1) & (t + 1 < NT);   // stage tile t+1 halves
        const bool sN2 = (t + 2 < NT);              // stage tile t+2 halves
        // ---- phase 0: quad (ih=0, jh=0) -----------------------------------
        LDA(afr, c, 0);
        LDB(b0f, c, 0);
        if (sN1) STAGE_A(t + 1, c ^ 1, 1);
        BARRIER();
        LGKM0();
        __builtin_amdgcn_s_setprio(1);
        MFMA16(0, 0, afr, b0f);
        __builtin_amdgcn_s_setprio(0);
        if (t == NT - 1) { VMCNT(0); } else { VMCNT(6); }
        BARRIER();
        // ---- phase 1: quad (0, 1) -----------------------------------------
        LDB(b1f, c, 1);
        if (sN1) STAGE_B(t + 1, c ^ 1, 1);
        BARRIER();
        LGKM0();
        __builtin_amdgcn_s_setprio(1);
        MFMA16(0, 2, afr, b1f);
        __builtin_amdgcn_s_setprio(0);
        BARRIER();
        // ---- phase 2: quad (1, 0) -----------------------------------------
        LDA(afr, c, 1);
        if (sN2) STAGE_A(t + 2, c, 0);
        BARRIER();
        LGKM0();
        __builtin_amdgcn_s_setprio(1);
        MFMA16(4, 0, afr, b0f);
        __builtin_amdgcn_s_setprio(0);
        BARRIER();
        // ---- phase 3: quad (1, 1) -----------------------------------------
        if (sN2) STAGE_B(t + 2, c, 0);
        BARRIER();
        LGKM0();
        __builtin_amdgcn_s_setprio(1);
        MFMA16(4, 2, afr, b1f);
        __builtin_amdgcn_s_setprio(0);
        if (sN2) { VMCNT(8); }
        else if (t + 2 == NT) { VMCNT(4); }
        BARRIER();
    }

    #pragma unroll
    for (int i = 0; i < 8; ++i) {
        int row = m0 + wm * 128 + i * 16 + lq * 4;
        #pragma unroll
        for (int j = 0; j < 4; ++j) {
            int col = n0 + wn * 64 + j * 16 + lr;
            if (col < N) {
                float bv = bias[col];
                #pragma unroll
                for (int r = 0; r < 4; ++r) {
                    float v = acc[i][j][r] + bv;
                    if (OUT_BF16)
                        ((unsigned short*)C)[(size_t)(row + r) * N + col] = f2bf(v);
                    else
                        ((float*)C)[(size_t)(row + r) * N + col] = v;   // plain store (no nt!)
                }
            }
        }
    }
#undef STAGE_A
#undef STAGE_B
#undef LDA
#undef LDB
#undef MFMA16
}

// ---------------- flash attention (causal), bf16 MFMA ----------------------
__global__ __launch_bounds__(256) void attn_kernel(const unsigned short* __restrict__ Q,
                                                   const unsigned short* __restrict__ K,
                                                   const unsigned short* __restrict__ V,
                                                   int ld,
                                                   float* __restrict__ O) {
    __shared__ __align__(16) unsigned short Ks[64 * 64];
    __shared__ __align__(16) unsigned short Vs[64 * 64];     // transposed [d][kv]
    __shared__ __align__(16) unsigned short Ps[4][16 * 64];  // per-wave P tile
    const int qb = blockIdx.x;
    const int bh = blockIdx.y;
    const int b = bh / NH, h = bh % NH;
    const int tid = threadIdx.x, lane = tid & 63, w = tid >> 6;
    const int lr = lane & 15, lq = lane >> 4;
    const int wq0 = qb * 64 + w * 16;
    const size_t base = (size_t)b * SEQ * ld + h * DH;
    const size_t obase = (size_t)b * SEQ * DM + h * DH;

    short8 qf[2];
    {
        const unsigned short* qp = Q + base + (size_t)(wq0 + lr) * ld + lq * 8;
        qf[0] = *reinterpret_cast<const short8*>(qp);
        qf[1] = *reinterpret_cast<const short8*>(qp + 32);
    }
    f32x4 o_acc[4] = {};
    float mrow[4], lrow[4];
    #pragma unroll
    for (int r = 0; r < 4; ++r) { mrow[r] = -1e30f; lrow[r] = 0.f; }

    const int srow = tid >> 3, scol = (tid & 7) * 8;
    for (int t = 0; t <= qb; ++t) {
        const int kv0 = t * 64;
        #pragma unroll
        for (int rr = 0; rr < 2; ++rr) {
            int row = rr * 32 + srow;
            {
                const unsigned short* kp = K + base + (size_t)(kv0 + row) * ld + scol;
                short8 v = *reinterpret_cast<const short8*>(kp);
                *reinterpret_cast<short8*>(&Ks[(row * 64 + scol) ^ ((row & 7) << 3)]) = v;
            }
            {
                const unsigned short* vp = V + base + (size_t)(kv0 + row) * ld + scol;
                short8 v = *reinterpret_cast<const short8*>(vp);
                #pragma unroll
                for (int j = 0; j < 8; ++j) {
                    int d = scol + j;
                    Vs[(d * 64 + row) ^ ((d & 7) << 3)] = (unsigned short)v[j];
                }
            }
        }
        __syncthreads();
        if (kv0 <= wq0 + 15) {
            f32x4 s[4];
            #pragma unroll
            for (int n = 0; n < 4; ++n) {
                int br = n * 16 + lr;
                short8 b0 = *reinterpret_cast<const short8*>(&Ks[(br * 64 + lq * 8) ^ ((br & 7) << 3)]);
                short8 b1 = *reinterpret_cast<const short8*>(&Ks[(br * 64 + 32 + lq * 8) ^ ((br & 7) << 3)]);
                f32x4 z = {};
                z = __builtin_amdgcn_mfma_f32_16x16x32_bf16(qf[0], b0, z, 0, 0, 0);
                z = __builtin_amdgcn_mfma_f32_16x16x32_bf16(qf[1], b1, z, 0, 0, 0);
                s[n] = z;
            }
            const bool diag = (t == qb);
            #pragma unroll
            for (int n = 0; n < 4; ++n)
                #pragma unroll
                for (int r = 0; r < 4; ++r) {
                    float v = s[n][r] * 0.125f;
                    if (diag) {
                        int rg = wq0 + lq * 4 + r;
                        int cg = kv0 + n * 16 + lr;
                        if (cg > rg) v = -1e30f;
                    }
                    s[n][r] = v;
                }
            float f[4];
            #pragma unroll
            for (int r = 0; r < 4; ++r) {
                float mx = fmaxf(fmaxf(s[0][r], s[1][r]), fmaxf(s[2][r], s[3][r]));
                #pragma unroll
                for (int off = 1; off < 16; off <<= 1) mx = fmaxf(mx, __shfl_xor(mx, off));
                float mn = fmaxf(mrow[r], mx);
                f[r] = exp2f((mrow[r] - mn) * 1.44269504f);
                mrow[r] = mn;
            }
            #pragma unroll
            for (int n = 0; n < 4; ++n)
                #pragma unroll
                for (int r = 0; r < 4; ++r)
                    s[n][r] = exp2f((s[n][r] - mrow[r]) * 1.44269504f);
            #pragma unroll
            for (int r = 0; r < 4; ++r) {
                float ls = ((s[0][r] + s[1][r]) + (s[2][r] + s[3][r]));
                #pragma unroll
                for (int off = 1; off < 16; off <<= 1) ls += __shfl_xor(ls, off);
                lrow[r] = lrow[r] * f[r] + ls;
            }
            #pragma unroll
            for (int n = 0; n < 4; ++n)
                #pragma unroll
                for (int r = 0; r < 4; ++r) {
                    int pr = lq * 4 + r, pc = n * 16 + lr;
                    Ps[w][(pr * 64 + pc) ^ ((pr & 7) << 3)] = f2bf(s[n][r]);
                }
            #pragma unroll
            for (int n = 0; n < 4; ++n)
                #pragma unroll
                for (int r = 0; r < 4; ++r) o_acc[n][r] *= f[r];
            #pragma unroll
            for (int kk = 0; kk < 2; ++kk) {
                short8 pa = *reinterpret_cast<const short8*>(
                    &Ps[w][(lr * 64 + kk * 32 + lq * 8) ^ ((lr & 7) << 3)]);
                #pragma unroll
                for (int n = 0; n < 4; ++n) {
                    int vr = n * 16 + lr;
                    short8 bv = *reinterpret_cast<const short8*>(
                        &Vs[(vr * 64 + kk * 32 + lq * 8) ^ ((vr & 7) << 3)]);
                    o_acc[n] = __builtin_amdgcn_mfma_f32_16x16x32_bf16(pa, bv, o_acc[n], 0, 0, 0);
                }
            }
        }
        __syncthreads();
    }
    #pragma unroll
    for (int r = 0; r < 4; ++r) {
        float inv = 1.f / lrow[r];
        int row = wq0 + lq * 4 + r;
        #pragma unroll
        for (int n = 0; n < 4; ++n)
            O[obase + (size_t)row * DM + n * 16 + lr] = o_acc[n][r] * inv;
    }
}

// ---------------------------------------------------------------------------
extern "C" void kernel_launch(void* const* d_in, const int* in_sizes, int n_in,
                              void* d_out, int out_size, void* d_ws, size_t ws_size,
                              hipStream_t stream) {
    const int*   tokens   = (const int*)d_in[0];
    const float* embed    = (const float*)d_in[1];
    const float* pe       = (const float*)d_in[2];
    const float* wq_w     = (const float*)d_in[3];
    const float* wq_b     = (const float*)d_in[4];
    const float* wk_w     = (const float*)d_in[5];
    const float* wk_b     = (const float*)d_in[6];
    const float* wv_w     = (const float*)d_in[7];
    const float* wv_b     = (const float*)d_in[8];
    const float* lin_w    = (const float*)d_in[9];
    const float* lin_b    = (const float*)d_in[10];
    const float* n1_s     = (const float*)d_in[11];
    const float* n1_b     = (const float*)d_in[12];
    const float* n2_s     = (const float*)d_in[13];
    const float* n2_b     = (const float*)d_in[14];
    const float* unemb_w  = (const float*)d_in[15];
    const float* unemb_b  = (const float*)d_in[16];

    char* ws = (char*)d_ws;
    size_t off = 0;
    auto carve = [&](size_t bytes) { char* p = ws + off; off += (bytes + 255) & ~(size_t)255; return p; };
    float*          xf     = (float*)carve((size_t)ROWS * DM * 4);
    float*          yb     = (float*)carve((size_t)ROWS * DM * 4);
    unsigned short* xb     = (unsigned short*)carve((size_t)ROWS * DM * 2);
    unsigned short* qkv    = (unsigned short*)carve((size_t)ROWS * QKVN * 2);
    unsigned short* wqkv_h = (unsigned short*)carve((size_t)NL * QKVN * DM * 2);
    unsigned short* lin_h  = (unsigned short*)carve((size_t)NL * DM * DM * 2);
    unsigned short* ue_h   = (unsigned short*)carve((size_t)VOCAB * DM * 2);
    float*          qkvb   = (float*)carve((size_t)NL * QKVN * 4);

    {
        int nq4 = NL * QKVN * DM / 4;
        cvt_qkv_kernel<<<(nq4 + 255) / 256, 256, 0, stream>>>(wq_w, wk_w, wv_w, wqkv_h, nq4);
        int nl4 = NL * DM * DM / 4;
        cvt_kernel<<<(nl4 + 255) / 256, 256, 0, stream>>>(lin_w, lin_h, nl4);
        int nu4 = VOCAB * DM / 4;
        cvt_kernel<<<(nu4 + 255) / 256, 256, 0, stream>>>(unemb_w, ue_h, nu4);
        pack_qkv_bias<<<(NL * QKVN + 255) / 256, 256, 0, stream>>>(wq_b, wk_b, wv_b, qkvb);
    }
    embed_kernel<<<ROWS, 256, 0, stream>>>(tokens, embed, pe, xf, xb);

    const int gx = ROWS / 128;   // 16 M-blocks (128-tile)
    for (int l = 0; l < NL; ++l) {
        gemm128<1><<<gx * (QKVN / 128), 256, 0, stream>>>(
            xb, wqkv_h + (size_t)l * QKVN * DM, qkvb + l * QKVN, qkv,
            ROWS, QKVN, DM, gx);
        attn_kernel<<<dim3(SEQ / 64, BATCH * NH), 256, 0, stream>>>(
            qkv, qkv + DM, qkv + 2 * DM, QKVN, yb);
        ln_kernel<<<ROWS, 256, 0, stream>>>(xf, yb, n1_s + l * DM, n1_b + l * DM, xf, xb);
        gemm128<0><<<gx * (DM / 128), 256, 0, stream>>>(
            xb, lin_h + (size_t)l * DM * DM, lin_b + l * DM, yb,
            ROWS, DM, DM, gx);
        ln_kernel<<<ROWS, 256, 0, stream>>>(xf, yb, n2_s + l * DM, n2_b + l * DM, xf, xb);
    }
    // unembed: [2048,768] x [50257,768]^T -> d_out fp32, rolled 8-phase GEMM
    const int gxu = ROWS / 256;                 // 8
    const int gyu = (VOCAB + 255) / 256;        // 197
    gemm256_8p<0><<<gxu * gyu, 512, 0, stream>>>(
        xb, ue_h, unemb_b, (float*)d_out, VOCAB, gxu);
}